// Round 3
// baseline (334.678 us; speedup 1.0000x reference)
//
#include <hip/hip_runtime.h>
#include <cfloat>

#define NBINS 25
#define RPB   128          // rows staged per block-iteration (51.2 KB LDS)
#define THREADS 256
#define GRID1 1024         // pass1 grid; partial-sum width

// Pass 1: stage 128 rows to LDS with fully-coalesced float4 loads, then
// 4 lanes per row compute softmax-confidence + argmax. Per-block partials
// (no global atomics) go to ws: part[slot*GRID1 + blk], slot = bin(0..24),
// 25+bin (sum_conf), 50+bin (sum_acc).
__launch_bounds__(THREADS, 3)
__global__ void ece_pass1(const float* __restrict__ logits,
                          const int* __restrict__ labels,
                          float* __restrict__ part, int n) {
    __shared__ float tile[RPB * 100];
    __shared__ float s_cnt[NBINS], s_conf[NBINS], s_acc[NBINS];
    const int t = threadIdx.x;
    if (t < NBINS) { s_cnt[t] = 0.f; s_conf[t] = 0.f; s_acc[t] = 0.f; }

    const int j = t & 3;    // sublane within 4-lane group
    const int g = t >> 2;   // group 0..63 within block

    for (int c = blockIdx.x; c * RPB < n; c += GRID1) {
        const int base = c * RPB;
        const int rows = min(RPB, n - base);
        const int nf4  = rows * 25;

        // ---- stage: contiguous float4 stream, 13 independent loads/thread
        const float4* src = reinterpret_cast<const float4*>(logits) + (size_t)base * 25;
        float4* dst = reinterpret_cast<float4*>(tile);
#pragma unroll
        for (int k = 0; k < 13; ++k) {
            const int idx = t + k * THREADS;           // < 3328; nf4 <= 3200
            if (idx < nf4) dst[idx] = src[idx];
        }
        __syncthreads();

        // ---- compute: 64 groups x 2 rows
#pragma unroll
        for (int rr = 0; rr < RPB; rr += 64) {
            const int r = rr + g;                      // < RPB always
            const float* rowp = tile + r * 100;
            float4 v[6];
#pragma unroll
            for (int k = 0; k < 6; ++k)
                v[k] = *reinterpret_cast<const float4*>(rowp + (j + 4 * k) * 4);
            const float x24 = rowp[96 + j];            // elements 96..99, one per lane

            // per-lane argmax, ascending index (first-occurrence ties)
            float m = v[0].x; int mi = 4 * j;
            if (v[0].y > m) { m = v[0].y; mi = 4 * j + 1; }
            if (v[0].z > m) { m = v[0].z; mi = 4 * j + 2; }
            if (v[0].w > m) { m = v[0].w; mi = 4 * j + 3; }
#pragma unroll
            for (int k = 1; k < 6; ++k) {
                const int idx = 4 * (j + 4 * k);
                if (v[k].x > m) { m = v[k].x; mi = idx; }
                if (v[k].y > m) { m = v[k].y; mi = idx + 1; }
                if (v[k].z > m) { m = v[k].z; mi = idx + 2; }
                if (v[k].w > m) { m = v[k].w; mi = idx + 3; }
            }
            if (x24 > m) { m = x24; mi = 96 + j; }
            // group-of-4 argmax reduce; smaller index wins ties
#pragma unroll
            for (int off = 1; off <= 2; off <<= 1) {
                const float om = __shfl_xor(m, off);
                const int   oi = __shfl_xor(mi, off);
                if (om > m || (om == m && oi < mi)) { m = om; mi = oi; }
            }
            // sum of exp(x - m): 25 per lane
            float s = __expf(x24 - m);
#pragma unroll
            for (int k = 0; k < 6; ++k) {
                s += __expf(v[k].x - m) + __expf(v[k].y - m) +
                     __expf(v[k].z - m) + __expf(v[k].w - m);
            }
#pragma unroll
            for (int off = 1; off <= 2; off <<= 1) s += __shfl_xor(s, off);

            if (j == 0 && r < rows) {
                const float conf = 1.0f / s;                       // exp(m-m)/sum
                int bin = (int)ceilf(conf * (float)NBINS) - 1;     // (i/25,(i+1)/25]
                bin = min(max(bin, 0), NBINS - 1);
                const float acc = (mi == labels[base + r]) ? 1.f : 0.f;
                atomicAdd(&s_cnt[bin], 1.f);
                atomicAdd(&s_conf[bin], conf);
                atomicAdd(&s_acc[bin], acc);
            }
        }
        __syncthreads();   // tile reuse barrier; also publishes LDS atomics
    }

    if (t < NBINS) {
        part[t * GRID1 + blockIdx.x]               = s_cnt[t];
        part[(NBINS + t) * GRID1 + blockIdx.x]     = s_conf[t];
        part[(2 * NBINS + t) * GRID1 + blockIdx.x] = s_acc[t];
    }
}

// Pass 2: reduce 75 x GRID1 partials, then the 25-term ECE sum.
__global__ void ece_final(const float* __restrict__ part, float* __restrict__ out, float n) {
    __shared__ float sacc[3 * NBINS];
    const int t = threadIdx.x;          // 1024 threads = 16 waves
    const int wave = t >> 6, lane = t & 63;
    for (int slot = wave; slot < 3 * NBINS; slot += 16) {
        const float* p = part + slot * GRID1;
        float s = 0.f;
        for (int k = lane; k < GRID1; k += 64) s += p[k];
#pragma unroll
        for (int off = 32; off; off >>= 1) s += __shfl_xor(s, off);
        if (lane == 0) sacc[slot] = s;
    }
    __syncthreads();
    if (t < 64) {
        float term = 0.f;
        if (t < NBINS) {
            const float cnt = sacc[t];
            const float sc  = sacc[NBINS + t];
            const float sa  = sacc[2 * NBINS + t];
            if (cnt > 0.f) {
                const float inv = 1.f / cnt;   // cnt >= 1 -> matches max(counts,1)
                term = fabsf(sc * inv - sa * inv) * (cnt / n);
            }
        }
#pragma unroll
        for (int off = 32; off; off >>= 1) term += __shfl_xor(term, off);
        if (t == 0) out[0] = term;
    }
}

extern "C" void kernel_launch(void* const* d_in, const int* in_sizes, int n_in,
                              void* d_out, int out_size, void* d_ws, size_t ws_size,
                              hipStream_t stream) {
    const float* logits = (const float*)d_in[0];
    const int*   labels = (const int*)d_in[1];
    float* part = (float*)d_ws;         // 75 * GRID1 floats = 300 KB, fully overwritten
    float* out  = (float*)d_out;
    const int n = in_sizes[1];          // number of rows / labels

    ece_pass1<<<GRID1, THREADS, 0, stream>>>(logits, labels, part, n);
    ece_final<<<1, 1024, 0, stream>>>(part, out, (float)n);
}